// Round 1
// baseline (228.922 us; speedup 1.0000x reference)
//
#include <hip/hip_runtime.h>
#include <math.h>

#define N_NODES 50000
#define N_EDGES 600000
#define ALPHA 0.01f

__device__ __forceinline__ float leaky(float x) { return x > 0.f ? x : ALPHA * x; }

// ---------------- K0: zero w[] + compute w_em = W_e @ W_m ----------------
__global__ void k0_prep(const float* __restrict__ W_e, const float* __restrict__ W_m,
                        float* __restrict__ w, float* __restrict__ w_em) {
    int tid = blockIdx.x * blockDim.x + threadIdx.x;
    for (int i = tid; i < N_NODES; i += gridDim.x * blockDim.x) w[i] = 0.f;
    if (blockIdx.x == 0 && threadIdx.x < 64) {
        float acc = 0.f;
        const float* row = W_e + threadIdx.x * 128;
        for (int k = 0; k < 128; ++k) acc += row[k] * W_m[k];
        w_em[threadIdx.x] = acc;
    }
}

// ---------------- K1: h_prime = leaky(h @ W_u); ps = hp·a1, pd = hp·a2 ----------------
// Block: 256 threads. 32 rows per block-iteration.
// Thread (rl = t>>5, c4 = t&31) owns rows {rl+8j, j<4} x cols {4*c4..4*c4+3}.
__global__ __launch_bounds__(256) void k1_node(
        const float* __restrict__ h, const float* __restrict__ Wu,
        const float* __restrict__ a,
        float* __restrict__ hp, float* __restrict__ ps, float* __restrict__ pd) {
    __shared__ float sh[32 * 132];   // 32 rows, padded stride 132 (bank-conflict-free)
    __shared__ float sa[256];
    int t = threadIdx.x;
    if (t < 256) sa[t] = a[t];
    int rl = t >> 5;
    int c4 = t & 31;

    for (int base = blockIdx.x * 32; base < N_NODES; base += gridDim.x * 32) {
        __syncthreads();
        // stage 32 h-rows into LDS (float4, guarded)
        for (int i = t; i < 32 * 32; i += 256) {
            int row = i >> 5, c = i & 31;
            float4 v = make_float4(0.f, 0.f, 0.f, 0.f);
            if (base + row < N_NODES)
                v = ((const float4*)h)[(size_t)(base + row) * 32 + c];
            *(float4*)(sh + row * 132 + c * 4) = v;
        }
        __syncthreads();

        float acc[4][4];
        #pragma unroll
        for (int j = 0; j < 4; ++j)
            #pragma unroll
            for (int x = 0; x < 4; ++x) acc[j][x] = 0.f;

        #pragma unroll 4
        for (int k = 0; k < 128; ++k) {
            float4 wv = ((const float4*)(Wu + k * 128))[c4];
            #pragma unroll
            for (int j = 0; j < 4; ++j) {
                float hv = sh[(rl + 8 * j) * 132 + k];
                acc[j][0] += hv * wv.x;
                acc[j][1] += hv * wv.y;
                acc[j][2] += hv * wv.z;
                acc[j][3] += hv * wv.w;
            }
        }

        int cb = c4 * 4;
        #pragma unroll
        for (int j = 0; j < 4; ++j) {
            int row = base + rl + 8 * j;
            float4 o;
            o.x = leaky(acc[j][0]);
            o.y = leaky(acc[j][1]);
            o.z = leaky(acc[j][2]);
            o.w = leaky(acc[j][3]);
            float p1 = o.x * sa[cb] + o.y * sa[cb + 1] + o.z * sa[cb + 2] + o.w * sa[cb + 3];
            float p2 = o.x * sa[128 + cb] + o.y * sa[128 + cb + 1] +
                       o.z * sa[128 + cb + 2] + o.w * sa[128 + cb + 3];
            #pragma unroll
            for (int m = 16; m >= 1; m >>= 1) {
                p1 += __shfl_xor(p1, m);
                p2 += __shfl_xor(p2, m);
            }
            if (row < N_NODES) {
                ((float4*)(hp + (size_t)row * 128))[c4] = o;
                if (c4 == 0) { ps[row] = p1; pd[row] = p2; }
            }
        }
    }
}

// ---------------- K2: per-edge z, p=exp(z), scatter w[src]+=p, S partials ----------------
// 16 lanes per edge (4 edges per wave). e-row read as float4/lane -> 256B coalesced.
__global__ __launch_bounds__(256) void k2_edge(
        const float* __restrict__ e, const int* __restrict__ src,
        const int* __restrict__ dst, const float* __restrict__ ps,
        const float* __restrict__ pd, const float* __restrict__ w_em,
        float* __restrict__ w, double* __restrict__ Spart) {
    __shared__ float swem[64];
    int t = threadIdx.x;
    if (t < 64) swem[t] = w_em[t];
    __syncthreads();

    int lane = t & 63;
    int q = lane & 15;
    int sub = lane >> 4;
    int gw = (blockIdx.x * 256 + t) >> 6;
    int nw = (gridDim.x * 256) >> 6;
    float4 wv = ((const float4*)swem)[q];

    double sacc = 0.0;
    for (int base = gw * 4; base < N_EDGES; base += nw * 4) {
        int eidx = base + sub;                       // E % 4 == 0 -> always valid
        float4 ev = ((const float4*)(e + (size_t)eidx * 64))[q];
        float d = ev.x * wv.x + ev.y * wv.y + ev.z * wv.z + ev.w * wv.w;
        d += __shfl_xor(d, 1);
        d += __shfl_xor(d, 2);
        d += __shfl_xor(d, 4);
        d += __shfl_xor(d, 8);
        if (q == 0) {
            int s  = src[eidx];
            float score = ps[s] + pd[dst[eidx]];
            float sig = 1.f / (1.f + expf(-score));
            float p = expf(sig * d);                 // z bounded ~(-1.2,1.2): no max-sub needed
            atomicAdd(&w[s], p);
            sacc += (double)p;
        }
    }
    __shared__ double sred[256];
    sred[t] = sacc;
    __syncthreads();
    for (int s2 = 128; s2 > 0; s2 >>= 1) {
        if (t < s2) sred[t] += sred[t + s2];
        __syncthreads();
    }
    if (t == 0) Spart[blockIdx.x] = sred[0];
}

// ---------------- K4: hgpart[b][col] = Σ_rows w[row]*leaky(hp[row][col]) ----------------
__global__ __launch_bounds__(256) void k4_hg(
        const float* __restrict__ hp, const float* __restrict__ w,
        double* __restrict__ hgpart) {
    int t = threadIdx.x;
    int col = t & 127;
    int half = t >> 7;
    double acc = 0.0;
    for (int r0 = blockIdx.x * 2; r0 < N_NODES; r0 += gridDim.x * 2) {
        int row = r0 + half;                          // N even -> always valid
        float wvv = w[row];
        float g = leaky(hp[(size_t)row * 128 + col]);
        acc += (double)(wvv * g);
    }
    __shared__ double sred[256];
    sred[t] = acc;
    __syncthreads();
    if (t < 128) hgpart[blockIdx.x * 128 + t] = sred[t] + sred[t + 128];
}

// ---------------- K5: reduce S + hg, then MLP 128->512->128->16->1 ----------------
__global__ __launch_bounds__(512) void k5_mlp(
        const double* __restrict__ Spart, int nsp,
        const double* __restrict__ hgpart, int nhg,
        const float* __restrict__ W1, const float* __restrict__ b1,
        const float* __restrict__ W2, const float* __restrict__ b2,
        const float* __restrict__ W3, const float* __restrict__ b3,
        const float* __restrict__ W4, const float* __restrict__ b4,
        float* __restrict__ out) {
    __shared__ float hgs[128];
    __shared__ float x1[512];
    __shared__ float x2[128];
    __shared__ float x3[16];
    __shared__ double dred[512];
    int t = threadIdx.x;

    double s = 0.0;
    for (int i = t; i < nsp; i += 512) s += Spart[i];
    dred[t] = s;
    __syncthreads();
    for (int st = 256; st > 0; st >>= 1) {
        if (t < st) dred[t] += dred[t + st];
        __syncthreads();
    }
    double S = dred[0];

    if (t < 128) {
        double a = 0.0;
        for (int b = 0; b < nhg; ++b) a += hgpart[b * 128 + t];
        hgs[t] = (float)(a / S);
    }
    __syncthreads();

    {   // x1 = relu(hg @ W1 + b1)   (coalesced over t)
        float acc = b1[t];
        #pragma unroll 4
        for (int d = 0; d < 128; ++d) acc += hgs[d] * W1[d * 512 + t];
        x1[t] = fmaxf(acc, 0.f);
    }
    __syncthreads();
    if (t < 128) {
        float acc = b2[t];
        #pragma unroll 4
        for (int k = 0; k < 512; ++k) acc += x1[k] * W2[k * 128 + t];
        x2[t] = fmaxf(acc, 0.f);
    }
    __syncthreads();
    if (t < 16) {
        float acc = b3[t];
        for (int k = 0; k < 128; ++k) acc += x2[k] * W3[k * 16 + t];
        x3[t] = fmaxf(acc, 0.f);
    }
    __syncthreads();
    if (t == 0) {
        float acc = b4[0];
        for (int k = 0; k < 16; ++k) acc += x3[k] * W4[k];
        out[0] = acc;
    }
}

extern "C" void kernel_launch(void* const* d_in, const int* in_sizes, int n_in,
                              void* d_out, int out_size, void* d_ws, size_t ws_size,
                              hipStream_t stream) {
    const float* h   = (const float*)d_in[0];
    const float* e   = (const float*)d_in[1];
    const int*   src = (const int*)d_in[2];
    const int*   dst = (const int*)d_in[3];
    const float* W_u = (const float*)d_in[4];
    const float* W_e = (const float*)d_in[5];
    const float* a   = (const float*)d_in[6];
    const float* W_m = (const float*)d_in[7];
    const float* W1  = (const float*)d_in[8];
    const float* b1  = (const float*)d_in[9];
    const float* W2  = (const float*)d_in[10];
    const float* b2  = (const float*)d_in[11];
    const float* W3  = (const float*)d_in[12];
    const float* b3  = (const float*)d_in[13];
    const float* W4  = (const float*)d_in[14];
    const float* b4  = (const float*)d_in[15];
    float* out = (float*)d_out;

    char* ws = (char*)d_ws;
    float*  hp    = (float*)(ws);                                   // 50000*128
    float*  ps    = (float*)(ws + 25600000);                        // 50000
    float*  pd    = (float*)(ws + 25800000);                        // 50000
    float*  w     = (float*)(ws + 26000000);                        // 50000
    float*  w_em  = (float*)(ws + 26200000);                        // 64
    double* Spart = (double*)(ws + 26200256);                       // 2048
    double* hgpart= (double*)(ws + 26216640);                       // 256*128
    // total ends at 26,478,784 bytes

    const int K2_GRID = 2048;
    const int K4_GRID = 256;

    hipLaunchKernelGGL(k0_prep, dim3(256), dim3(256), 0, stream, W_e, W_m, w, w_em);
    hipLaunchKernelGGL(k1_node, dim3(1563), dim3(256), 0, stream, h, W_u, a, hp, ps, pd);
    hipLaunchKernelGGL(k2_edge, dim3(K2_GRID), dim3(256), 0, stream,
                       e, src, dst, ps, pd, w_em, w, Spart);
    hipLaunchKernelGGL(k4_hg, dim3(K4_GRID), dim3(256), 0, stream, hp, w, hgpart);
    hipLaunchKernelGGL(k5_mlp, dim3(1), dim3(512), 0, stream,
                       Spart, K2_GRID, hgpart, K4_GRID,
                       W1, b1, W2, b2, W3, b3, W4, b4, out);
}

// Round 2
// 132.816 us; speedup vs baseline: 1.7236x; 1.7236x over previous
//
#include <hip/hip_runtime.h>
#include <math.h>

#define N_NODES 50000
#define N_EDGES 600000
#define ALPHA 0.01f
#define K2_GRID 2048
#define K4_GRID 256

__device__ __forceinline__ float leaky(float x) { return x > 0.f ? x : ALPHA * x; }

// ---------------- K0: zero w[] + compute w_em = W_e @ W_m ----------------
__global__ void k0_prep(const float* __restrict__ W_e, const float* __restrict__ W_m,
                        float* __restrict__ w, float* __restrict__ w_em) {
    int tid = blockIdx.x * blockDim.x + threadIdx.x;
    for (int i = tid; i < N_NODES; i += gridDim.x * blockDim.x) w[i] = 0.f;
    if (blockIdx.x == 0 && threadIdx.x < 64) {
        float acc = 0.f;
        const float* row = W_e + threadIdx.x * 128;
        for (int k = 0; k < 128; ++k) acc += row[k] * W_m[k];
        w_em[threadIdx.x] = acc;
    }
}

// ---------------- K1: h_prime = leaky(h @ W_u); ps = hp·a1, pd = hp·a2 ----------------
__global__ __launch_bounds__(256) void k1_node(
        const float* __restrict__ h, const float* __restrict__ Wu,
        const float* __restrict__ a,
        float* __restrict__ hp, float* __restrict__ ps, float* __restrict__ pd) {
    __shared__ float sh[32 * 132];
    __shared__ float sa[256];
    int t = threadIdx.x;
    if (t < 256) sa[t] = a[t];
    int rl = t >> 5;
    int c4 = t & 31;

    for (int base = blockIdx.x * 32; base < N_NODES; base += gridDim.x * 32) {
        __syncthreads();
        for (int i = t; i < 32 * 32; i += 256) {
            int row = i >> 5, c = i & 31;
            float4 v = make_float4(0.f, 0.f, 0.f, 0.f);
            if (base + row < N_NODES)
                v = ((const float4*)h)[(size_t)(base + row) * 32 + c];
            *(float4*)(sh + row * 132 + c * 4) = v;
        }
        __syncthreads();

        float acc[4][4];
        #pragma unroll
        for (int j = 0; j < 4; ++j)
            #pragma unroll
            for (int x = 0; x < 4; ++x) acc[j][x] = 0.f;

        #pragma unroll 4
        for (int k = 0; k < 128; ++k) {
            float4 wv = ((const float4*)(Wu + k * 128))[c4];
            #pragma unroll
            for (int j = 0; j < 4; ++j) {
                float hv = sh[(rl + 8 * j) * 132 + k];
                acc[j][0] += hv * wv.x;
                acc[j][1] += hv * wv.y;
                acc[j][2] += hv * wv.z;
                acc[j][3] += hv * wv.w;
            }
        }

        int cb = c4 * 4;
        #pragma unroll
        for (int j = 0; j < 4; ++j) {
            int row = base + rl + 8 * j;
            float4 o;
            o.x = leaky(acc[j][0]);
            o.y = leaky(acc[j][1]);
            o.z = leaky(acc[j][2]);
            o.w = leaky(acc[j][3]);
            float p1 = o.x * sa[cb] + o.y * sa[cb + 1] + o.z * sa[cb + 2] + o.w * sa[cb + 3];
            float p2 = o.x * sa[128 + cb] + o.y * sa[128 + cb + 1] +
                       o.z * sa[128 + cb + 2] + o.w * sa[128 + cb + 3];
            #pragma unroll
            for (int m = 16; m >= 1; m >>= 1) {
                p1 += __shfl_xor(p1, m);
                p2 += __shfl_xor(p2, m);
            }
            if (row < N_NODES) {
                ((float4*)(hp + (size_t)row * 128))[c4] = o;
                if (c4 == 0) { ps[row] = p1; pd[row] = p2; }
            }
        }
    }
}

// ---------------- K2: per-edge z, p=exp(z), scatter w[src]+=p, S partials ----------------
__global__ __launch_bounds__(256) void k2_edge(
        const float* __restrict__ e, const int* __restrict__ src,
        const int* __restrict__ dst, const float* __restrict__ ps,
        const float* __restrict__ pd, const float* __restrict__ w_em,
        float* __restrict__ w, double* __restrict__ Spart) {
    __shared__ float swem[64];
    int t = threadIdx.x;
    if (t < 64) swem[t] = w_em[t];
    __syncthreads();

    int lane = t & 63;
    int q = lane & 15;
    int sub = lane >> 4;
    int gw = (blockIdx.x * 256 + t) >> 6;
    int nw = (gridDim.x * 256) >> 6;
    float4 wv = ((const float4*)swem)[q];

    double sacc = 0.0;
    for (int base = gw * 4; base < N_EDGES; base += nw * 4) {
        int eidx = base + sub;
        float4 ev = ((const float4*)(e + (size_t)eidx * 64))[q];
        float d = ev.x * wv.x + ev.y * wv.y + ev.z * wv.z + ev.w * wv.w;
        d += __shfl_xor(d, 1);
        d += __shfl_xor(d, 2);
        d += __shfl_xor(d, 4);
        d += __shfl_xor(d, 8);
        if (q == 0) {
            int s  = src[eidx];
            float score = ps[s] + pd[dst[eidx]];
            float sig = 1.f / (1.f + expf(-score));
            float p = expf(sig * d);
            atomicAdd(&w[s], p);
            sacc += (double)p;
        }
    }
    __shared__ double sred[256];
    sred[t] = sacc;
    __syncthreads();
    for (int s2 = 128; s2 > 0; s2 >>= 1) {
        if (t < s2) sred[t] += sred[t + s2];
        __syncthreads();
    }
    if (t == 0) Spart[blockIdx.x] = sred[0];
}

// ---------------- K4: hgpart[b][col] = Σ_rows w[row]*leaky(hp[row][col]) ----------------
__global__ __launch_bounds__(256) void k4_hg(
        const float* __restrict__ hp, const float* __restrict__ w,
        double* __restrict__ hgpart) {
    int t = threadIdx.x;
    int col = t & 127;
    int half = t >> 7;
    double acc = 0.0;
    for (int r0 = blockIdx.x * 2; r0 < N_NODES; r0 += gridDim.x * 2) {
        int row = r0 + half;
        float wvv = w[row];
        float g = leaky(hp[(size_t)row * 128 + col]);
        acc += (double)(wvv * g);
    }
    __shared__ double sred[256];
    sred[t] = acc;
    __syncthreads();
    if (t < 128) hgpart[blockIdx.x * 128 + t] = sred[t] + sred[t + 128];
}

// ---------------- K5a: reduce S + hg columns -> hg[128] (float, already /S) ----------------
__global__ __launch_bounds__(1024) void k5a_reduce(
        const double* __restrict__ Spart, const double* __restrict__ hgpart,
        float* __restrict__ hg) {
    __shared__ double dred[1024];
    __shared__ double S_sh;
    int t = threadIdx.x;
    double s = Spart[t] + Spart[t + 1024];          // K2_GRID == 2048
    dred[t] = s;
    __syncthreads();
    for (int st = 512; st > 0; st >>= 1) {
        if (t < st) dred[t] += dred[t + st];
        __syncthreads();
    }
    if (t == 0) S_sh = dred[0];

    int c = t & 127, g = t >> 7;                    // 8 b-groups x 128 cols
    double a = 0.0;
    #pragma unroll 4
    for (int i = 0; i < 32; ++i)                    // K4_GRID == 256 = 8*32
        a += hgpart[(size_t)(g + 8 * i) * 128 + c];
    __syncthreads();
    dred[t] = a;
    __syncthreads();
    if (t < 128) {
        double tot = 0.0;
        #pragma unroll
        for (int g2 = 0; g2 < 8; ++g2) tot += dred[t + 128 * g2];
        hg[t] = (float)(tot / S_sh);
    }
}

// ---------------- K5b: x1 = relu(hg @ W1 + b1), 16 blocks x 32 outputs ----------------
__global__ __launch_bounds__(512) void k5b_l1(
        const float* __restrict__ hg, const float* __restrict__ W1,
        const float* __restrict__ b1, float* __restrict__ x1) {
    __shared__ float hgs[128];
    __shared__ float part[16][32];
    int t = threadIdx.x;
    if (t < 128) hgs[t] = hg[t];
    __syncthreads();
    int o = t & 31, g = t >> 5;                     // 32 outputs, 16 d-groups of 8
    int og = blockIdx.x * 32 + o;
    float acc = 0.f;
    #pragma unroll
    for (int i = 0; i < 8; ++i) {
        int d = g * 8 + i;
        acc += hgs[d] * W1[d * 512 + og];
    }
    part[g][o] = acc;
    __syncthreads();
    if (t < 32) {
        float s = b1[blockIdx.x * 32 + t];
        #pragma unroll
        for (int g2 = 0; g2 < 16; ++g2) s += part[g2][t];
        x1[blockIdx.x * 32 + t] = fmaxf(s, 0.f);
    }
}

// ---------------- K5c: x2 = relu(x1 @ W2 + b2), 8 blocks x 16 outputs ----------------
__global__ __launch_bounds__(512) void k5c_l2(
        const float* __restrict__ x1, const float* __restrict__ W2,
        const float* __restrict__ b2, float* __restrict__ x2) {
    __shared__ float x1s[512];
    __shared__ float part[32][16];
    int t = threadIdx.x;
    x1s[t] = x1[t];
    __syncthreads();
    int o = t & 15, g = t >> 4;                     // 16 outputs, 32 k-groups of 16
    int og = blockIdx.x * 16 + o;
    float acc = 0.f;
    #pragma unroll
    for (int i = 0; i < 16; ++i) {
        int k = g * 16 + i;
        acc += x1s[k] * W2[k * 128 + og];
    }
    part[g][o] = acc;
    __syncthreads();
    if (t < 16) {
        float s = b2[blockIdx.x * 16 + t];
        #pragma unroll
        for (int g2 = 0; g2 < 32; ++g2) s += part[g2][t];
        x2[blockIdx.x * 16 + t] = fmaxf(s, 0.f);
    }
}

// ---------------- K5d: x3 = relu(x2 @ W3 + b3); out = x3 @ W4 + b4 ----------------
__global__ __launch_bounds__(64) void k5d_tail(
        const float* __restrict__ x2, const float* __restrict__ W3,
        const float* __restrict__ b3, const float* __restrict__ W4,
        const float* __restrict__ b4, float* __restrict__ out) {
    int t = threadIdx.x;                            // 1 wave
    int o = t & 15, g = t >> 4;                     // 16 outputs, 4 k-groups of 32
    float acc = 0.f;
    #pragma unroll 8
    for (int i = 0; i < 32; ++i) {
        int k = g * 32 + i;
        acc += x2[k] * W3[k * 16 + o];
    }
    acc += __shfl_xor(acc, 16);
    acc += __shfl_xor(acc, 32);
    float x3 = fmaxf(acc + b3[o], 0.f);
    float v = (t < 16) ? x3 * W4[t] : 0.f;
    #pragma unroll
    for (int m = 8; m >= 1; m >>= 1) v += __shfl_xor(v, m);
    if (t == 0) out[0] = v + b4[0];
}

extern "C" void kernel_launch(void* const* d_in, const int* in_sizes, int n_in,
                              void* d_out, int out_size, void* d_ws, size_t ws_size,
                              hipStream_t stream) {
    const float* h   = (const float*)d_in[0];
    const float* e   = (const float*)d_in[1];
    const int*   src = (const int*)d_in[2];
    const int*   dst = (const int*)d_in[3];
    const float* W_u = (const float*)d_in[4];
    const float* W_e = (const float*)d_in[5];
    const float* a   = (const float*)d_in[6];
    const float* W_m = (const float*)d_in[7];
    const float* W1  = (const float*)d_in[8];
    const float* b1  = (const float*)d_in[9];
    const float* W2  = (const float*)d_in[10];
    const float* b2  = (const float*)d_in[11];
    const float* W3  = (const float*)d_in[12];
    const float* b3  = (const float*)d_in[13];
    const float* W4  = (const float*)d_in[14];
    const float* b4  = (const float*)d_in[15];
    float* out = (float*)d_out;

    char* ws = (char*)d_ws;
    float*  hp    = (float*)(ws);                                   // 50000*128 f
    float*  ps    = (float*)(ws + 25600000);                        // 50000 f
    float*  pd    = (float*)(ws + 25800000);                        // 50000 f
    float*  w     = (float*)(ws + 26000000);                        // 50000 f
    float*  w_em  = (float*)(ws + 26200000);                        // 64 f
    double* Spart = (double*)(ws + 26200256);                       // 2048 d
    double* hgpart= (double*)(ws + 26216640);                       // 256*128 d
    float*  hg    = (float*)(ws + 26478784);                        // 128 f
    float*  x1v   = (float*)(ws + 26479296);                        // 512 f
    float*  x2v   = (float*)(ws + 26481344);                        // 128 f
    // total ends at 26,481,856 bytes

    hipLaunchKernelGGL(k0_prep, dim3(256), dim3(256), 0, stream, W_e, W_m, w, w_em);
    hipLaunchKernelGGL(k1_node, dim3(1563), dim3(256), 0, stream, h, W_u, a, hp, ps, pd);
    hipLaunchKernelGGL(k2_edge, dim3(K2_GRID), dim3(256), 0, stream,
                       e, src, dst, ps, pd, w_em, w, Spart);
    hipLaunchKernelGGL(k4_hg, dim3(K4_GRID), dim3(256), 0, stream, hp, w, hgpart);
    hipLaunchKernelGGL(k5a_reduce, dim3(1), dim3(1024), 0, stream, Spart, hgpart, hg);
    hipLaunchKernelGGL(k5b_l1, dim3(16), dim3(512), 0, stream, hg, W1, b1, x1v);
    hipLaunchKernelGGL(k5c_l2, dim3(8), dim3(512), 0, stream, x1v, W2, b2, x2v);
    hipLaunchKernelGGL(k5d_tail, dim3(1), dim3(64), 0, stream, x2v, W3, b3, W4, b4, out);
}